// Round 9
// baseline (239.950 us; speedup 1.0000x reference)
//
#include <hip/hip_runtime.h>
#include <hip/hip_bf16.h>

#define N 20000
#define E 200000
#define IN 128
#define OUT 128
#define NB 8
#define SI 16
#define SO 16
#define R 230
#define T 365

// Message-aggregation accumulator in module .bss (10.24 MB) — d_ws is left
// completely untouched, and kernel_launch makes no runtime API calls at all
// (kernel launches only) for maximum graph-capture safety.
__device__ float g_agg[(size_t)N * OUT];

__global__ void zero_agg_kernel() {
    long i = (long)blockIdx.x * blockDim.x + threadIdx.x;
    long stride = (long)gridDim.x * blockDim.x;
    for (; i < (long)N * OUT; i += stride) g_agg[i] = 0.f;
}

// One thread per (edge, out_feature). o = b*16 + ol.
// msg[e,o] = (sum_i h[src, b*16+i] * W[r, b, i, ol]) * edge_norm[e]
__global__ void edge_kernel(const float* __restrict__ h,
                            const float* __restrict__ edge_norm,
                            const float* __restrict__ weight,
                            const int* __restrict__ edge_src,
                            const int* __restrict__ edge_dst,
                            const int* __restrict__ edge_type) {
    long idx = (long)blockIdx.x * blockDim.x + threadIdx.x;
    int e = (int)(idx >> 7);
    if (e >= E) return;
    int o  = (int)(idx & 127);
    int b  = o >> 4;
    int ol = o & 15;
    int s = edge_src[e];
    int d = edge_dst[e];
    int r = edge_type[e];
    const float* src = h + (long)s * IN + b * SI;
    const float* W   = weight + (long)r * (NB * SI * SO) + b * (SI * SO) + ol;
    float acc = 0.f;
#pragma unroll
    for (int i = 0; i < SI; ++i)
        acc = fmaf(src[i], W[i * SO], acc);
    acc *= edge_norm[e];
    atomicAdd(&g_agg[(long)d * OUT + o], acc);
}

// 16 nodes per block, 128 threads (thread = out feature).
// loop_weight read from global (64 KB, L1/L2-resident, coalesced);
// h rows staged in 8 KB LDS (read back as lane-broadcast float4).
__global__ __launch_bounds__(128) void node_kernel(
        const float* __restrict__ h,
        const float* __restrict__ node_norm,
        const float* __restrict__ h_bias,
        const float* __restrict__ loop_weight,
        const float* __restrict__ time_embed,
        const int* __restrict__ time_idx,
        float* __restrict__ out) {
    __shared__ float hsm[IN * 16];   // hsm[i*16 + nl]
    const int tid  = threadIdx.x;    // 0..127 = output feature
    const int base = blockIdx.x * 16;

    // hsm[i][nl] = h[(base+nl)*128 + i]; k = nl*128 + i => coalesced loads
    for (int k = tid; k < 16 * IN; k += 128) {
        int nl = k >> 7;
        int i  = k & 127;
        hsm[i * 16 + nl] = h[(long)(base + nl) * IN + i];
    }
    __syncthreads();

    float acc[16];
#pragma unroll
    for (int nl = 0; nl < 16; ++nl) acc[nl] = 0.f;

    for (int i = 0; i < IN; ++i) {
        float w = loop_weight[(long)i * OUT + tid];
        const float4* hp = reinterpret_cast<const float4*>(&hsm[i * 16]);
#pragma unroll
        for (int q = 0; q < 4; ++q) {
            float4 hv = hp[q];   // broadcast across lanes
            acc[q * 4 + 0] = fmaf(hv.x, w, acc[q * 4 + 0]);
            acc[q * 4 + 1] = fmaf(hv.y, w, acc[q * 4 + 1]);
            acc[q * 4 + 2] = fmaf(hv.z, w, acc[q * 4 + 2]);
            acc[q * 4 + 3] = fmaf(hv.w, w, acc[q * 4 + 3]);
        }
    }

    float bias = h_bias[tid];
#pragma unroll
    for (int nl = 0; nl < 16; ++nl) {
        int n = base + nl;
        float v = g_agg[(long)n * OUT + tid] * node_norm[n] + bias + acc[nl];
        out[(long)n * OUT + tid] = fmaxf(v, 0.f);
        // Output 1: time_embed[time_idx[n]], f32 passthrough
        out[(long)N * OUT + (long)n * IN + tid] =
            time_embed[(long)time_idx[n] * IN + tid];
    }
}

extern "C" void kernel_launch(void* const* d_in, const int* in_sizes, int n_in,
                              void* d_out, int out_size, void* d_ws, size_t ws_size,
                              hipStream_t stream) {
    const float* h           = (const float*)d_in[0];
    const float* edge_norm   = (const float*)d_in[1];
    const float* node_norm   = (const float*)d_in[2];
    const float* weight      = (const float*)d_in[3];
    const float* h_bias      = (const float*)d_in[4];
    const float* loop_weight = (const float*)d_in[5];
    const float* time_embed  = (const float*)d_in[6];
    const int*   edge_src    = (const int*)d_in[7];
    const int*   edge_dst    = (const int*)d_in[8];
    const int*   edge_type   = (const int*)d_in[9];
    const int*   time_idx    = (const int*)d_in[10];
    float* out = (float*)d_out;

    zero_agg_kernel<<<2560, 256, 0, stream>>>();

    const long total = (long)E * 128;
    const int  bs = 256;
    edge_kernel<<<(int)((total + bs - 1) / bs), bs, 0, stream>>>(
        h, edge_norm, weight, edge_src, edge_dst, edge_type);

    node_kernel<<<N / 16, 128, 0, stream>>>(
        h, node_norm, h_bias, loop_weight, time_embed, time_idx, out);
}